// Round 6
// baseline (4513.119 us; speedup 1.0000x reference)
//
#include <hip/hip_runtime.h>
#include <math.h>

// Problem constants
#define NWIN 512     // 8x8x8 windows
#define NHD  3       // heads
#define NTOK 343     // 7x7x7 tokens per window
#define HD   32      // head dim
#define CH   96      // channels
#define DIM  56      // spatial dim
#define CHUNK 32     // tokens per staged chunk

__device__ __forceinline__ unsigned short f2h_bits(float x) {
    _Float16 h = (_Float16)x;                  // RNE
    return __builtin_bit_cast(unsigned short, h);
}
__device__ __forceinline__ float h2f_bits(unsigned short u) {
    return (float)__builtin_bit_cast(_Float16, u);
}

__device__ __forceinline__ float grp32_sum(float v) {
    v += __shfl_xor(v, 16, 32);
    v += __shfl_xor(v, 8, 32);
    v += __shfl_xor(v, 4, 32);
    v += __shfl_xor(v, 2, 32);
    v += __shfl_xor(v, 1, 32);
    return v;  // all 32 lanes hold the sum
}

#define FMA4(acc, xv, wv)                      \
    acc = fmaf((xv).x, (wv).x, acc);           \
    acc = fmaf((xv).y, (wv).y, acc);           \
    acc = fmaf((xv).z, (wv).z, acc);           \
    acc = fmaf((xv).w, (wv).w, acc);

// One block per (head, window).
// Phase A: single pass over x -> q,k,v (b128 GEMM, weights in LDS transposed);
//          k-transform -> ksum,kv,v16; q-transform -> qfin cached in y.
// Phase B: read qfin from y, z + att, overwrite y (no staging, no barriers).
// Phase C: depthwise 5x5x5 conv on v16, y += fm + bias.
__global__ __launch_bounds__(256, 2) void attn_kernel(
    const float* __restrict__ x, const float* __restrict__ w_qkv,
    const float* __restrict__ scale_param, const float* __restrict__ pos_enc,
    const float* __restrict__ dwc_w, const float* __restrict__ dwc_b,
    float* __restrict__ y)
{
    __shared__ unsigned short v16[NTOK * HD];            // 21952 B (fp16 v)
    __shared__ union UW {
        float wT[3 * HD * 100];                          // 38400 B: wT[m][c][cc] pitch 100
        float dwc[HD * 125];                             // 16000 B (phase C alias)
    } uw;
    __shared__ float xs[CHUNK * CH];                     // 12288 B
    __shared__ union UK { float kq[CHUNK * HD]; float red[256]; } uk; // 4096 B
    __shared__ float kv_lds[HD * HD];                    // 4096 B
    __shared__ float ksum_s[HD];
    __shared__ float sps[HD];
    // total 81088 B -> 2 blocks/CU (81920 limit)

    const int tid = threadIdx.x;
    const int bid = blockIdx.x;
    const int h   = bid >> 9;        // head 0..2
    const int win = bid & 511;
    const int wd  = win >> 6, wh = (win >> 3) & 7, ww = win & 7;
    const int g8  = tid >> 5;        // token group 0..7 (4 tokens each)
    const int c   = tid & 31;        // channel lane

    // stage transposed weights wT[m][cl][cc] (pitch 100 floats) + softplus(scale)
    for (int i = tid; i < 3 * CH * HD; i += 256) {
        int m = i / (CH * HD); int r = i - m * (CH * HD);
        int cc = r >> 5, cl = r & 31;
        uw.wT[(m * HD + cl) * 100 + cc] = w_qkv[cc * 288 + m * CH + h * HD + cl];
    }
    if (tid < HD) {
        float sv = scale_param[tid];
        sps[tid] = (sv > 20.f) ? sv : log1pf(expf(sv));
    }
    __syncthreads();
    const float spc = sps[c];

    const int cb = tid >> 3, d0 = (tid & 7) * 4;   // owned kv row / col group
    float kva[4] = {0.f, 0.f, 0.f, 0.f};
    float ksum_reg = 0.f;

    const float4* wq4 = (const float4*)&uw.wT[(0 * HD + c) * 100];
    const float4* wk4 = (const float4*)&uw.wT[(1 * HD + c) * 100];
    const float4* wv4 = (const float4*)&uw.wT[(2 * HD + c) * 100];
    const int qq0 = (c >> 3) * 6;    // rotated cc start -> conflict-free w reads

    // ================= Phase A: q,k,v -> ksum, kv, v16, qfin->y ==========
    for (int jc = 0; jc < NTOK; jc += CHUNK) {
        const int nj = min(CHUNK, NTOK - jc);
        // stage x chunk (float4, coalesced)
        const int nf4 = nj * (CH / 4);
        for (int i = tid; i < nf4; i += 256) {
            int r = i / 24, c4 = i - r * 24;
            int j2 = jc + r;
            int dz = j2 / 49, rem = j2 - dz * 49;
            int dy = rem / 7, dx = rem - dy * 7;
            int tok = ((wd * 7 + dz) * DIM + (wh * 7 + dy)) * DIM + (ww * 7 + dx);
            ((float4*)xs)[i] = ((const float4*)(x + (size_t)tok * CH))[c4];
        }
        __syncthreads();

        // q,k,v GEMM: 4 tokens x 3 outputs per thread, all-b128 LDS reads
        float qa[4] = {0.f, 0.f, 0.f, 0.f};
        float ka[4] = {0.f, 0.f, 0.f, 0.f};
        float va[4] = {0.f, 0.f, 0.f, 0.f};
        const float4* xr4 = (const float4*)&xs[(g8 * 4) * CH];
        int qq = qq0;
        #pragma unroll
        for (int cq = 0; cq < 24; ++cq) {
            float4 wq_ = wq4[qq], wk_ = wk4[qq], wv_ = wv4[qq];
            float4 x0 = xr4[qq], x1 = xr4[24 + qq], x2 = xr4[48 + qq], x3 = xr4[72 + qq];
            FMA4(qa[0], x0, wq_); FMA4(qa[1], x1, wq_);
            FMA4(qa[2], x2, wq_); FMA4(qa[3], x3, wq_);
            FMA4(ka[0], x0, wk_); FMA4(ka[1], x1, wk_);
            FMA4(ka[2], x2, wk_); FMA4(ka[3], x3, wk_);
            FMA4(va[0], x0, wv_); FMA4(va[1], x1, wv_);
            FMA4(va[2], x2, wv_); FMA4(va[3], x3, wv_);
            qq = (qq == 23) ? 0 : qq + 1;
        }

        // k-transform + q-transform + v store + qfin->y
        #pragma unroll
        for (int i2 = 0; i2 < 4; ++i2) {
            int t = g8 * 4 + i2;
            int j = jc + t;
            bool valid = (t < nj);             // group-uniform
            int jj = valid ? j : 0;
            float kacc = ka[i2] + pos_enc[jj * HD + c];
            float kp = (fmaxf(kacc, 0.f) + 1e-6f) / spc;
            float n2k = grp32_sum(kp * kp);
            float k3 = kp * kp * kp;
            float n6k = grp32_sum(k3 * k3);
            float kfin = k3 * sqrtf(n2k / n6k);

            float qp = (fmaxf(qa[i2], 0.f) + 1e-6f) / spc;
            float n2q = grp32_sum(qp * qp);
            float q3 = qp * qp * qp;
            float n6q = grp32_sum(q3 * q3);
            float qfin = q3 * sqrtf(n2q / n6q);

            if (valid) {
                v16[j * HD + c]    = f2h_bits(va[i2]);
                uk.kq[t * HD + c]  = kfin;
                ksum_reg += kfin;
                int dz = j / 49, rem = j - dz * 49, dy = rem / 7, dx = rem - dy * 7;
                int tok = ((wd * 7 + dz) * DIM + (wh * 7 + dy)) * DIM + (ww * 7 + dx);
                y[(size_t)tok * CH + h * HD + c] = qfin;   // cache qfin in-place
            }
        }
        __syncthreads();

        // kv accumulation (row cb, cols d0..d0+3) over this chunk
        for (int j = 0; j < nj; ++j) {
            float kk = uk.kq[j * HD + cb];
            uint2 vv = *(const uint2*)&v16[(jc + j) * HD + d0];
            kva[0] = fmaf(kk, h2f_bits((unsigned short)(vv.x & 0xffff)), kva[0]);
            kva[1] = fmaf(kk, h2f_bits((unsigned short)(vv.x >> 16)),    kva[1]);
            kva[2] = fmaf(kk, h2f_bits((unsigned short)(vv.y & 0xffff)), kva[2]);
            kva[3] = fmaf(kk, h2f_bits((unsigned short)(vv.y >> 16)),    kva[3]);
        }
        // next iter's post-stage barrier protects kq/xs reuse
    }

    __syncthreads();                 // all kv-accum kq reads done (red aliases kq)
    uk.red[tid] = ksum_reg;
    kv_lds[cb * HD + d0 + 0] = kva[0];
    kv_lds[cb * HD + d0 + 1] = kva[1];
    kv_lds[cb * HD + d0 + 2] = kva[2];
    kv_lds[cb * HD + d0 + 3] = kva[3];
    __syncthreads();
    if (tid < HD) {
        float s2 = 0.f;
        #pragma unroll
        for (int gg = 0; gg < 8; ++gg) s2 += uk.red[gg * HD + tid];
        ksum_s[tid] = s2;
    }
    __syncthreads();

    const float ks_c   = ksum_s[c];
    const float bias_c = dwc_b[c];
    float kvc[HD];                      // kv column c in registers
    #pragma unroll
    for (int c2 = 0; c2 < HD; ++c2) kvc[c2] = kv_lds[c2 * HD + c];

    // ================= Phase B: qfin(y) -> z, att, write y ================
    for (int jc = 0; jc < NTOK; jc += CHUNK) {
        const int nj = min(CHUNK, NTOK - jc);
        float zreg[4]; int tokr[4];
        #pragma unroll
        for (int i2 = 0; i2 < 4; ++i2) {
            int t = g8 * 4 + i2;
            int j = jc + t;
            bool valid = (t < nj);
            int jj = valid ? j : 0;
            int dz = jj / 49, rem = jj - dz * 49, dy = rem / 7, dx = rem - dy * 7;
            int tok = ((wd * 7 + dz) * DIM + (wh * 7 + dy)) * DIM + (ww * 7 + dx);
            float qf = y[(size_t)tok * CH + h * HD + c];   // thread-local RAW
            zreg[i2] = 1.f / (grp32_sum(qf * ks_c) + 1e-6f);
            if (valid) uk.kq[t * HD + c] = qf;   // same-wave write->read (in-order LDS)
            tokr[i2] = tok;
        }
        #pragma unroll
        for (int i2 = 0; i2 < 4; ++i2) {
            int t = g8 * 4 + i2;
            if (t < nj) {
                float att = 0.f;
                #pragma unroll
                for (int c2 = 0; c2 < HD; c2 += 4) {
                    float4 qv = *(const float4*)&uk.kq[t * HD + c2];
                    att = fmaf(qv.x, kvc[c2],     att);
                    att = fmaf(qv.y, kvc[c2 + 1], att);
                    att = fmaf(qv.z, kvc[c2 + 2], att);
                    att = fmaf(qv.w, kvc[c2 + 3], att);
                }
                y[(size_t)tokr[i2] * CH + h * HD + c] = att * zreg[i2];
            }
        }
        // kq reuse is same-wave only -> no barrier needed
    }

    __threadfence_block();   // B's y writes visible to conv RMW
    __syncthreads();

    // ---------------- Phase C: depthwise 5x5x5 conv, y += fm + bias ----
    for (int i = tid; i < HD * 125; i += 256) uw.dwc[i] = dwc_w[i];
    __syncthreads();

    for (int it = g8; it < 49; it += 8) {
        int dz = it / 7, dy = it - dz * 7;
        float fm[7] = {0.f, 0.f, 0.f, 0.f, 0.f, 0.f, 0.f};
        #pragma unroll
        for (int ka2 = 0; ka2 < 5; ++ka2) {
            int za = dz + ka2 - 2;
            if ((unsigned)za >= 7u) continue;
            #pragma unroll
            for (int kb = 0; kb < 5; ++kb) {
                int zb = dy + kb - 2;
                if ((unsigned)zb >= 7u) continue;
                const unsigned short* vb = &v16[(za * 49 + zb * 7) * HD + c];
                float vr[7];
                #pragma unroll
                for (int xx = 0; xx < 7; ++xx) vr[xx] = h2f_bits(vb[xx * HD]);
                const float* wb = &uw.dwc[c * 125 + ka2 * 25 + kb * 5];
                float w0 = wb[0], w1 = wb[1], w2 = wb[2], w3 = wb[3], w4 = wb[4];
                #pragma unroll
                for (int dx2 = 0; dx2 < 7; ++dx2) {
                    if (dx2 - 2 >= 0) fm[dx2] = fmaf(vr[dx2 - 2], w0, fm[dx2]);
                    if (dx2 - 1 >= 0) fm[dx2] = fmaf(vr[dx2 - 1], w1, fm[dx2]);
                    fm[dx2] = fmaf(vr[dx2], w2, fm[dx2]);
                    if (dx2 + 1 <= 6) fm[dx2] = fmaf(vr[dx2 + 1], w3, fm[dx2]);
                    if (dx2 + 2 <= 6) fm[dx2] = fmaf(vr[dx2 + 2], w4, fm[dx2]);
                }
            }
        }
        int tokbase = ((wd * 7 + dz) * DIM + (wh * 7 + dy)) * DIM + ww * 7;
        #pragma unroll
        for (int dx2 = 0; dx2 < 7; ++dx2) {
            float* yp = &y[(size_t)(tokbase + dx2) * CH + h * HD + c];
            *yp += fm[dx2] + bias_c;
        }
    }
}

// In-place projection: d_out <- d_out @ w_proj + b_proj.
__global__ __launch_bounds__(256, 1) void proj_kernel(
    const float* __restrict__ wp, const float* __restrict__ bp,
    float* __restrict__ y)
{
    __shared__ float yt[256 * 97];   // 99328 B, pad->conflict-free
    __shared__ float wl[96 * 96];    // 36864 B

    const int tid = threadIdx.x;
    const int base = blockIdx.x * 256;

    for (int i = tid; i < 96 * 96; i += 256) wl[i] = wp[i];
    for (int i = tid; i < 256 * 96; i += 256) {
        int r = i / 96; int ch2 = i - r * 96;
        yt[r * 97 + ch2] = y[(base + r) * 96 + ch2];
    }
    __syncthreads();

    const int tokg = tid & 63;
    const int outg = tid >> 6;

    float acc[4][24];
    #pragma unroll
    for (int jj = 0; jj < 24; ++jj) {
        float b = bp[outg * 24 + jj];
        acc[0][jj] = b; acc[1][jj] = b; acc[2][jj] = b; acc[3][jj] = b;
    }

    for (int cc = 0; cc < 96; ++cc) {
        float y0 = yt[(tokg)       * 97 + cc];
        float y1 = yt[(tokg + 64)  * 97 + cc];
        float y2 = yt[(tokg + 128) * 97 + cc];
        float y3 = yt[(tokg + 192) * 97 + cc];
        const float* wrow = &wl[cc * 96 + outg * 24];
        #pragma unroll
        for (int jj = 0; jj < 24; ++jj) {
            float wvv = wrow[jj];
            acc[0][jj] = fmaf(y0, wvv, acc[0][jj]);
            acc[1][jj] = fmaf(y1, wvv, acc[1][jj]);
            acc[2][jj] = fmaf(y2, wvv, acc[2][jj]);
            acc[3][jj] = fmaf(y3, wvv, acc[3][jj]);
        }
    }
    __syncthreads();   // all reads done before in-place writes (same block only)

    #pragma unroll
    for (int i = 0; i < 4; ++i) {
        int tok = base + tokg + 64 * i;
        #pragma unroll
        for (int jj = 0; jj < 24; ++jj)
            y[tok * 96 + outg * 24 + jj] = acc[i][jj];
    }
}

extern "C" void kernel_launch(void* const* d_in, const int* in_sizes, int n_in,
                              void* d_out, int out_size, void* d_ws, size_t ws_size,
                              hipStream_t stream) {
    const float* x           = (const float*)d_in[0];
    const float* w_qkv       = (const float*)d_in[1];
    const float* scale_param = (const float*)d_in[2];
    const float* pos_enc     = (const float*)d_in[3];
    const float* dwc_w       = (const float*)d_in[4];
    const float* dwc_b       = (const float*)d_in[5];
    const float* w_proj      = (const float*)d_in[6];
    const float* b_proj      = (const float*)d_in[7];
    float* out = (float*)d_out;

    attn_kernel<<<dim3(NHD * NWIN), dim3(256), 0, stream>>>(
        x, w_qkv, scale_param, pos_enc, dwc_w, dwc_b, out);
    proj_kernel<<<dim3(686), dim3(256), 0, stream>>>(w_proj, b_proj, out);
}

// Round 7
// 576.186 us; speedup vs baseline: 7.8327x; 7.8327x over previous
//
#include <hip/hip_runtime.h>
#include <math.h>

// Problem constants
#define NWIN 512     // 8x8x8 windows
#define NHD  3       // heads
#define NTOK 343     // 7x7x7 tokens per window
#define HD   32      // head dim
#define CH   96      // channels
#define DIM  56      // spatial dim
#define CHUNK 32     // tokens per staged chunk

__device__ __forceinline__ unsigned short f2h_bits(float x) {
    _Float16 h = (_Float16)x;                  // RNE
    return __builtin_bit_cast(unsigned short, h);
}
__device__ __forceinline__ float h2f_bits(unsigned short u) {
    return (float)__builtin_bit_cast(_Float16, u);
}

__device__ __forceinline__ float grp32_sum(float v) {
    v += __shfl_xor(v, 16, 32);
    v += __shfl_xor(v, 8, 32);
    v += __shfl_xor(v, 4, 32);
    v += __shfl_xor(v, 2, 32);
    v += __shfl_xor(v, 1, 32);
    return v;  // all 32 lanes hold the sum
}

#define FMA4(acc, xv, wv)                      \
    acc = fmaf((xv).x, (wv).x, acc);           \
    acc = fmaf((xv).y, (wv).y, acc);           \
    acc = fmaf((xv).z, (wv).z, acc);           \
    acc = fmaf((xv).w, (wv).w, acc);

// One block per (head, window).
// Phase A: single pass over x -> q,k,v (b128 GEMM, weights in LDS transposed,
//          STATIC indices, unroll 2 -> no spill); k-transform -> ksum,kv,v16;
//          q-transform -> qfin cached in y (thread-local same-address RAW).
// Phase B: read qfin from y, z + att, overwrite y (no staging, no barriers).
// Phase C: depthwise 5x5x5 conv on v16, y += fm + bias.
__global__ __launch_bounds__(256, 2) void attn_kernel(
    const float* __restrict__ x, const float* __restrict__ w_qkv,
    const float* __restrict__ scale_param, const float* __restrict__ pos_enc,
    const float* __restrict__ dwc_w, const float* __restrict__ dwc_b,
    float* __restrict__ y)
{
    __shared__ unsigned short v16[NTOK * HD];            // 21952 B (fp16 v)
    __shared__ union UW {
        float wT[3 * HD * 100];                          // 38400 B: wT[m][c][cc] pitch 100
        float dwc[HD * 125];                             // 16000 B (phase C alias)
    } uw;
    __shared__ float xs[CHUNK * CH];                     // 12288 B
    __shared__ union UK { float kq[CHUNK * HD]; float red[256]; } uk; // 4096 B
    __shared__ float kv_lds[HD * HD];                    // 4096 B
    __shared__ float ksum_s[HD];
    __shared__ float sps[HD];
    // total 81088 B -> 2 blocks/CU (81920 limit)

    const int tid = threadIdx.x;
    const int bid = blockIdx.x;
    const int h   = bid >> 9;        // head 0..2
    const int win = bid & 511;
    const int wd  = win >> 6, wh = (win >> 3) & 7, ww = win & 7;
    const int g8  = tid >> 5;        // token group 0..7 (4 tokens each)
    const int c   = tid & 31;        // channel lane

    // stage transposed weights wT[m][cl][cc] (pitch 100 floats) + softplus(scale)
    for (int i = tid; i < 3 * CH * HD; i += 256) {
        int m = i / (CH * HD); int r = i - m * (CH * HD);
        int cc = r >> 5, cl = r & 31;
        uw.wT[(m * HD + cl) * 100 + cc] = w_qkv[cc * 288 + m * CH + h * HD + cl];
    }
    if (tid < HD) {
        float sv = scale_param[tid];
        sps[tid] = (sv > 20.f) ? sv : log1pf(expf(sv));
    }
    __syncthreads();
    const float spc = sps[c];

    const int cb = tid >> 3, d0 = (tid & 7) * 4;   // owned kv row / col group
    float kva[4] = {0.f, 0.f, 0.f, 0.f};
    float ksum_reg = 0.f;

    const float4* wq4 = (const float4*)&uw.wT[(0 * HD + c) * 100];
    const float4* wk4 = (const float4*)&uw.wT[(1 * HD + c) * 100];
    const float4* wv4 = (const float4*)&uw.wT[(2 * HD + c) * 100];

    // ================= Phase A: q,k,v -> ksum, kv, v16, qfin->y ==========
    for (int jc = 0; jc < NTOK; jc += CHUNK) {
        const int nj = min(CHUNK, NTOK - jc);
        // stage x chunk (float4, coalesced)
        const int nf4 = nj * (CH / 4);
        for (int i = tid; i < nf4; i += 256) {
            int r = i / 24, c4 = i - r * 24;
            int j2 = jc + r;
            int dz = j2 / 49, rem = j2 - dz * 49;
            int dy = rem / 7, dx = rem - dy * 7;
            int tok = ((wd * 7 + dz) * DIM + (wh * 7 + dy)) * DIM + (ww * 7 + dx);
            ((float4*)xs)[i] = ((const float4*)(x + (size_t)tok * CH))[c4];
        }
        __syncthreads();

        // q,k,v GEMM: 4 tokens x 3 outputs per thread, b128 LDS reads,
        // STATIC indices, unroll 2 (register-pressure-safe)
        float qa[4] = {0.f, 0.f, 0.f, 0.f};
        float ka[4] = {0.f, 0.f, 0.f, 0.f};
        float va[4] = {0.f, 0.f, 0.f, 0.f};
        const float4* xr4 = (const float4*)&xs[(g8 * 4) * CH];
        #pragma unroll 2
        for (int cq = 0; cq < 24; ++cq) {
            float4 wq_ = wq4[cq], wk_ = wk4[cq], wv_ = wv4[cq];
            float4 x0 = xr4[cq], x1 = xr4[24 + cq], x2 = xr4[48 + cq], x3 = xr4[72 + cq];
            FMA4(qa[0], x0, wq_); FMA4(qa[1], x1, wq_);
            FMA4(qa[2], x2, wq_); FMA4(qa[3], x3, wq_);
            FMA4(ka[0], x0, wk_); FMA4(ka[1], x1, wk_);
            FMA4(ka[2], x2, wk_); FMA4(ka[3], x3, wk_);
            FMA4(va[0], x0, wv_); FMA4(va[1], x1, wv_);
            FMA4(va[2], x2, wv_); FMA4(va[3], x3, wv_);
        }

        // k-transform + q-transform + v store + qfin->y
        #pragma unroll
        for (int i2 = 0; i2 < 4; ++i2) {
            int t = g8 * 4 + i2;
            int j = jc + t;
            bool valid = (t < nj);             // group-uniform
            int jj = valid ? j : 0;
            float kacc = ka[i2] + pos_enc[jj * HD + c];
            float kp = (fmaxf(kacc, 0.f) + 1e-6f) / spc;
            float n2k = grp32_sum(kp * kp);
            float k3 = kp * kp * kp;
            float n6k = grp32_sum(k3 * k3);
            float kfin = k3 * sqrtf(n2k / n6k);

            float qp = (fmaxf(qa[i2], 0.f) + 1e-6f) / spc;
            float n2q = grp32_sum(qp * qp);
            float q3 = qp * qp * qp;
            float n6q = grp32_sum(q3 * q3);
            float qfin = q3 * sqrtf(n2q / n6q);

            if (valid) {
                v16[j * HD + c]    = f2h_bits(va[i2]);
                uk.kq[t * HD + c]  = kfin;
                ksum_reg += kfin;
                int dz = j / 49, rem = j - dz * 49, dy = rem / 7, dx = rem - dy * 7;
                int tok = ((wd * 7 + dz) * DIM + (wh * 7 + dy)) * DIM + (ww * 7 + dx);
                y[(size_t)tok * CH + h * HD + c] = qfin;   // cache qfin in-place
            }
        }
        __syncthreads();

        // kv accumulation (row cb, cols d0..d0+3) over this chunk
        for (int j = 0; j < nj; ++j) {
            float kk = uk.kq[j * HD + cb];
            uint2 vv = *(const uint2*)&v16[(jc + j) * HD + d0];
            kva[0] = fmaf(kk, h2f_bits((unsigned short)(vv.x & 0xffff)), kva[0]);
            kva[1] = fmaf(kk, h2f_bits((unsigned short)(vv.x >> 16)),    kva[1]);
            kva[2] = fmaf(kk, h2f_bits((unsigned short)(vv.y & 0xffff)), kva[2]);
            kva[3] = fmaf(kk, h2f_bits((unsigned short)(vv.y >> 16)),    kva[3]);
        }
        // next iter's post-stage barrier protects kq/xs reuse
    }

    __syncthreads();                 // all kv-accum kq reads done (red aliases kq)
    uk.red[tid] = ksum_reg;
    kv_lds[cb * HD + d0 + 0] = kva[0];
    kv_lds[cb * HD + d0 + 1] = kva[1];
    kv_lds[cb * HD + d0 + 2] = kva[2];
    kv_lds[cb * HD + d0 + 3] = kva[3];
    __syncthreads();
    if (tid < HD) {
        float s2 = 0.f;
        #pragma unroll
        for (int gg = 0; gg < 8; ++gg) s2 += uk.red[gg * HD + tid];
        ksum_s[tid] = s2;
    }
    __syncthreads();

    const float ks_c   = ksum_s[c];
    const float bias_c = dwc_b[c];
    float kvc[HD];                      // kv column c in registers
    #pragma unroll
    for (int c2 = 0; c2 < HD; ++c2) kvc[c2] = kv_lds[c2 * HD + c];

    // ================= Phase B: qfin(y) -> z, att, write y ================
    for (int jc = 0; jc < NTOK; jc += CHUNK) {
        const int nj = min(CHUNK, NTOK - jc);
        float zreg[4]; int tokr[4];
        #pragma unroll
        for (int i2 = 0; i2 < 4; ++i2) {
            int t = g8 * 4 + i2;
            int j = jc + t;
            bool valid = (t < nj);
            int jj = valid ? j : 0;
            int dz = jj / 49, rem = jj - dz * 49, dy = rem / 7, dx = rem - dy * 7;
            int tok = ((wd * 7 + dz) * DIM + (wh * 7 + dy)) * DIM + (ww * 7 + dx);
            float qf = y[(size_t)tok * CH + h * HD + c];   // thread-local RAW
            zreg[i2] = 1.f / (grp32_sum(qf * ks_c) + 1e-6f);
            if (valid) uk.kq[t * HD + c] = qf;   // same-wave write->read (in-order LDS)
            tokr[i2] = tok;
        }
        #pragma unroll
        for (int i2 = 0; i2 < 4; ++i2) {
            int t = g8 * 4 + i2;
            if (t < nj) {
                float att = 0.f;
                #pragma unroll
                for (int c2 = 0; c2 < HD; c2 += 4) {
                    float4 qv = *(const float4*)&uk.kq[t * HD + c2];
                    att = fmaf(qv.x, kvc[c2],     att);
                    att = fmaf(qv.y, kvc[c2 + 1], att);
                    att = fmaf(qv.z, kvc[c2 + 2], att);
                    att = fmaf(qv.w, kvc[c2 + 3], att);
                }
                y[(size_t)tokr[i2] * CH + h * HD + c] = att * zreg[i2];
            }
        }
        // kq rows touched are group-private -> no barrier needed
    }

    __threadfence_block();   // B's y writes visible to conv RMW
    __syncthreads();

    // ---------------- Phase C: depthwise 5x5x5 conv, y += fm + bias ----
    for (int i = tid; i < HD * 125; i += 256) uw.dwc[i] = dwc_w[i];
    __syncthreads();

    for (int it = g8; it < 49; it += 8) {
        int dz = it / 7, dy = it - dz * 7;
        float fm[7] = {0.f, 0.f, 0.f, 0.f, 0.f, 0.f, 0.f};
        #pragma unroll
        for (int ka2 = 0; ka2 < 5; ++ka2) {
            int za = dz + ka2 - 2;
            if ((unsigned)za >= 7u) continue;
            #pragma unroll
            for (int kb = 0; kb < 5; ++kb) {
                int zb = dy + kb - 2;
                if ((unsigned)zb >= 7u) continue;
                const unsigned short* vb = &v16[(za * 49 + zb * 7) * HD + c];
                float vr[7];
                #pragma unroll
                for (int xx = 0; xx < 7; ++xx) vr[xx] = h2f_bits(vb[xx * HD]);
                const float* wb = &uw.dwc[c * 125 + ka2 * 25 + kb * 5];
                float w0 = wb[0], w1 = wb[1], w2 = wb[2], w3 = wb[3], w4 = wb[4];
                #pragma unroll
                for (int dx2 = 0; dx2 < 7; ++dx2) {
                    if (dx2 - 2 >= 0) fm[dx2] = fmaf(vr[dx2 - 2], w0, fm[dx2]);
                    if (dx2 - 1 >= 0) fm[dx2] = fmaf(vr[dx2 - 1], w1, fm[dx2]);
                    fm[dx2] = fmaf(vr[dx2], w2, fm[dx2]);
                    if (dx2 + 1 <= 6) fm[dx2] = fmaf(vr[dx2 + 1], w3, fm[dx2]);
                    if (dx2 + 2 <= 6) fm[dx2] = fmaf(vr[dx2 + 2], w4, fm[dx2]);
                }
            }
        }
        int tokbase = ((wd * 7 + dz) * DIM + (wh * 7 + dy)) * DIM + ww * 7;
        #pragma unroll
        for (int dx2 = 0; dx2 < 7; ++dx2) {
            float* yp = &y[(size_t)(tokbase + dx2) * CH + h * HD + c];
            *yp += fm[dx2] + bias_c;
        }
    }
}

// In-place projection: d_out <- d_out @ w_proj + b_proj.
__global__ __launch_bounds__(256, 1) void proj_kernel(
    const float* __restrict__ wp, const float* __restrict__ bp,
    float* __restrict__ y)
{
    __shared__ float yt[256 * 97];   // 99328 B, pad->conflict-free
    __shared__ float wl[96 * 96];    // 36864 B

    const int tid = threadIdx.x;
    const int base = blockIdx.x * 256;

    for (int i = tid; i < 96 * 96; i += 256) wl[i] = wp[i];
    for (int i = tid; i < 256 * 96; i += 256) {
        int r = i / 96; int ch2 = i - r * 96;
        yt[r * 97 + ch2] = y[(base + r) * 96 + ch2];
    }
    __syncthreads();

    const int tokg = tid & 63;
    const int outg = tid >> 6;

    float acc[4][24];
    #pragma unroll
    for (int jj = 0; jj < 24; ++jj) {
        float b = bp[outg * 24 + jj];
        acc[0][jj] = b; acc[1][jj] = b; acc[2][jj] = b; acc[3][jj] = b;
    }

    for (int cc = 0; cc < 96; ++cc) {
        float y0 = yt[(tokg)       * 97 + cc];
        float y1 = yt[(tokg + 64)  * 97 + cc];
        float y2 = yt[(tokg + 128) * 97 + cc];
        float y3 = yt[(tokg + 192) * 97 + cc];
        const float* wrow = &wl[cc * 96 + outg * 24];
        #pragma unroll
        for (int jj = 0; jj < 24; ++jj) {
            float wvv = wrow[jj];
            acc[0][jj] = fmaf(y0, wvv, acc[0][jj]);
            acc[1][jj] = fmaf(y1, wvv, acc[1][jj]);
            acc[2][jj] = fmaf(y2, wvv, acc[2][jj]);
            acc[3][jj] = fmaf(y3, wvv, acc[3][jj]);
        }
    }
    __syncthreads();   // all reads done before in-place writes (same block only)

    #pragma unroll
    for (int i = 0; i < 4; ++i) {
        int tok = base + tokg + 64 * i;
        #pragma unroll
        for (int jj = 0; jj < 24; ++jj)
            y[tok * 96 + outg * 24 + jj] = acc[i][jj];
    }
}

extern "C" void kernel_launch(void* const* d_in, const int* in_sizes, int n_in,
                              void* d_out, int out_size, void* d_ws, size_t ws_size,
                              hipStream_t stream) {
    const float* x           = (const float*)d_in[0];
    const float* w_qkv       = (const float*)d_in[1];
    const float* scale_param = (const float*)d_in[2];
    const float* pos_enc     = (const float*)d_in[3];
    const float* dwc_w       = (const float*)d_in[4];
    const float* dwc_b       = (const float*)d_in[5];
    const float* w_proj      = (const float*)d_in[6];
    const float* b_proj      = (const float*)d_in[7];
    float* out = (float*)d_out;

    attn_kernel<<<dim3(NHD * NWIN), dim3(256), 0, stream>>>(
        x, w_qkv, scale_param, pos_enc, dwc_w, dwc_b, out);
    proj_kernel<<<dim3(686), dim3(256), 0, stream>>>(w_proj, b_proj, out);
}

// Round 8
// 452.715 us; speedup vs baseline: 9.9690x; 1.2727x over previous
//
#include <hip/hip_runtime.h>
#include <math.h>

// Problem constants
#define NWIN 512     // 8x8x8 windows
#define NHD  3       // heads
#define NTOK 343     // 7x7x7 tokens per window
#define HD   32      // head dim
#define CH   96      // channels
#define DIM  56      // spatial dim
#define TCH  64      // Phase A tokens per chunk (lane = token)
#define BCH  32      // Phase B tokens per chunk

__device__ __forceinline__ unsigned short f2h_bits(float x) {
    _Float16 h = (_Float16)x;                  // RNE
    return __builtin_bit_cast(unsigned short, h);
}
__device__ __forceinline__ float h2f_bits(unsigned short u) {
    return (float)__builtin_bit_cast(_Float16, u);
}

__device__ __forceinline__ float grp32_sum(float v) {
    v += __shfl_xor(v, 16, 32);
    v += __shfl_xor(v, 8, 32);
    v += __shfl_xor(v, 4, 32);
    v += __shfl_xor(v, 2, 32);
    v += __shfl_xor(v, 1, 32);
    return v;
}

// 24 FMAs against wave-uniform weight rows (s_load broadcast expected).
#define PROCW(xv, WR)                                                   \
  { const float4 q0 = *(const float4*)(WR);                             \
    const float4 q1 = *(const float4*)((WR) + 4);                       \
    const float4 k0 = *(const float4*)((WR) + CH);                      \
    const float4 k1 = *(const float4*)((WR) + CH + 4);                  \
    const float4 v0 = *(const float4*)((WR) + 2 * CH);                  \
    const float4 v1 = *(const float4*)((WR) + 2 * CH + 4);              \
    aq[0] = fmaf(xv, q0.x, aq[0]); aq[1] = fmaf(xv, q0.y, aq[1]);       \
    aq[2] = fmaf(xv, q0.z, aq[2]); aq[3] = fmaf(xv, q0.w, aq[3]);       \
    aq[4] = fmaf(xv, q1.x, aq[4]); aq[5] = fmaf(xv, q1.y, aq[5]);       \
    aq[6] = fmaf(xv, q1.z, aq[6]); aq[7] = fmaf(xv, q1.w, aq[7]);       \
    ak[0] = fmaf(xv, k0.x, ak[0]); ak[1] = fmaf(xv, k0.y, ak[1]);       \
    ak[2] = fmaf(xv, k0.z, ak[2]); ak[3] = fmaf(xv, k0.w, ak[3]);       \
    ak[4] = fmaf(xv, k1.x, ak[4]); ak[5] = fmaf(xv, k1.y, ak[5]);       \
    ak[6] = fmaf(xv, k1.z, ak[6]); ak[7] = fmaf(xv, k1.w, ak[7]);       \
    av[0] = fmaf(xv, v0.x, av[0]); av[1] = fmaf(xv, v0.y, av[1]);       \
    av[2] = fmaf(xv, v0.z, av[2]); av[3] = fmaf(xv, v0.w, av[3]);       \
    av[4] = fmaf(xv, v1.x, av[4]); av[5] = fmaf(xv, v1.y, av[5]);       \
    av[6] = fmaf(xv, v1.z, av[6]); av[7] = fmaf(xv, v1.w, av[7]); }

// One block per (head, window), 256 threads, target 4 blocks/CU (LDS 38.8KB).
// Phase A (lane = token, wave = 8-channel slice): q,k,v GEMM with x from
// global (prefetch-1) and weights via wave-uniform s_load broadcast;
// channel-norm transforms via cross-wave LDS reduction; kfin->kq(LDS),
// v->v16(LDS, fp16), qfin->y(global cache); kv accumulation per chunk.
// Phase B: qfin(y) -> z + att (round-7 mapping), overwrite y.
// Phase C: depthwise 5x5x5 conv on v16, y += fm + bias.
__global__ __launch_bounds__(256, 4) void attn_kernel(
    const float* __restrict__ x, const float* __restrict__ w_qkv,
    const float* __restrict__ scale_param, const float* __restrict__ pos_enc,
    const float* __restrict__ dwc_w, const float* __restrict__ dwc_b,
    float* __restrict__ y)
{
    __shared__ __align__(16) unsigned short v16[NTOK * HD];   // 21952 B
    __shared__ __align__(16) union UU {
        struct AA {
            float kq[TCH * 33];          // 8448 B (pitch 33: conflict-free)
            float red[4][4][64];         // 4096 B (cross-wave norm partials)
            float kv[HD * HD];           // 4096 B
        } a;                             // Phase B reuses kq[0..1023] as kqB
        float dwc[HD * 125];             // 16000 B (Phase C alias)
    } u;
    __shared__ float ksum_s[HD];
    __shared__ float sps[HD];
    // total 38848 B -> 4 blocks/CU

    const int tid = threadIdx.x, bid = blockIdx.x;
    const int h = bid >> 9, win = bid & 511;
    const int wd = win >> 6, wh = (win >> 3) & 7, ww = win & 7;
    const int wv = tid >> 6, lane = tid & 63;
    const int c8 = __builtin_amdgcn_readfirstlane((tid >> 6) << 3); // wave channel base

    if (tid < HD) {
        float sv = scale_param[tid];
        sps[tid] = (sv > 20.f) ? sv : log1pf(expf(sv));
    }
    __syncthreads();
    float sp8[8];
    #pragma unroll
    for (int i = 0; i < 8; ++i) sp8[i] = sps[c8 + i];

    const int cb = tid >> 3, d0 = (tid & 7) * 4;   // kv-accum ownership
    float kva[4] = {0.f, 0.f, 0.f, 0.f};
    float ksp[8] = {0.f, 0.f, 0.f, 0.f, 0.f, 0.f, 0.f, 0.f};
    const float* wbase = w_qkv + h * HD + c8;      // wave-uniform

    // ================= Phase A =================
    for (int jc = 0; jc < NTOK; jc += TCH) {
        const int nj = min(TCH, NTOK - jc);
        const int tl = jc + lane;
        const bool tval = tl < NTOK;
        const int tc = tval ? tl : NTOK - 1;       // clamped (safe loads)
        int dz = tc / 49, rem = tc - dz * 49, dy = rem / 7, dxx = rem - dy * 7;
        const int gtok = ((wd * 7 + dz) * DIM + (wh * 7 + dy)) * DIM + (ww * 7 + dxx);
        const float4* xg = (const float4*)(x + (size_t)gtok * CH);

        float aq[8] = {0,0,0,0,0,0,0,0};
        float ak[8] = {0,0,0,0,0,0,0,0};
        float av[8] = {0,0,0,0,0,0,0,0};
        float4 xc = xg[0];
        #pragma unroll 1
        for (int c4 = 0; c4 < 24; ++c4) {
            float4 xn = (c4 < 23) ? xg[c4 + 1] : xc;   // prefetch next
            const float* wr = wbase + c4 * 4 * 288;
            PROCW(xc.x, wr);
            PROCW(xc.y, wr + 288);
            PROCW(xc.z, wr + 576);
            PROCW(xc.w, wr + 864);
            xc = xn;
        }

        // transforms: all channel-local, then cross-wave norm reduce
        float pe[8];
        *(float4*)&pe[0] = *(const float4*)(pos_enc + tc * HD + c8);
        *(float4*)&pe[4] = *(const float4*)(pos_enc + tc * HD + c8 + 4);
        float k3[8], q3[8];
        float n2k = 0.f, n6k = 0.f, n2q = 0.f, n6q = 0.f;
        #pragma unroll
        for (int i = 0; i < 8; ++i) {
            float kk = ak[i] + pe[i];
            float kp = (fmaxf(kk, 0.f) + 1e-6f) / sp8[i];
            n2k = fmaf(kp, kp, n2k);
            float t3 = kp * kp * kp; k3[i] = t3;
            n6k = fmaf(t3, t3, n6k);
            float qp = (fmaxf(aq[i], 0.f) + 1e-6f) / sp8[i];
            n2q = fmaf(qp, qp, n2q);
            float u3 = qp * qp * qp; q3[i] = u3;
            n6q = fmaf(u3, u3, n6q);
        }
        u.a.red[0][wv][lane] = n2k;
        u.a.red[1][wv][lane] = n6k;
        u.a.red[2][wv][lane] = n2q;
        u.a.red[3][wv][lane] = n6q;
        __syncthreads();   // also guarantees prev chunk's kv-accum kq reads done
        float N2k = u.a.red[0][0][lane] + u.a.red[0][1][lane] + u.a.red[0][2][lane] + u.a.red[0][3][lane];
        float N6k = u.a.red[1][0][lane] + u.a.red[1][1][lane] + u.a.red[1][2][lane] + u.a.red[1][3][lane];
        float N2q = u.a.red[2][0][lane] + u.a.red[2][1][lane] + u.a.red[2][2][lane] + u.a.red[2][3][lane];
        float N6q = u.a.red[3][0][lane] + u.a.red[3][1][lane] + u.a.red[3][2][lane] + u.a.red[3][3][lane];
        float sk = sqrtf(N2k / N6k), sq = sqrtf(N2q / N6q);

        if (tval) {
            float kf[8], qf[8];
            #pragma unroll
            for (int i = 0; i < 8; ++i) {
                kf[i] = k3[i] * sk;
                ksp[i] += kf[i];
                qf[i] = q3[i] * sq;
            }
            *(float4*)&u.a.kq[lane * 33 + c8]     = make_float4(kf[0], kf[1], kf[2], kf[3]);
            *(float4*)&u.a.kq[lane * 33 + c8 + 4] = make_float4(kf[4], kf[5], kf[6], kf[7]);
            uint4 pk;
            pk.x = (unsigned)f2h_bits(av[0]) | ((unsigned)f2h_bits(av[1]) << 16);
            pk.y = (unsigned)f2h_bits(av[2]) | ((unsigned)f2h_bits(av[3]) << 16);
            pk.z = (unsigned)f2h_bits(av[4]) | ((unsigned)f2h_bits(av[5]) << 16);
            pk.w = (unsigned)f2h_bits(av[6]) | ((unsigned)f2h_bits(av[7]) << 16);
            *(uint4*)&v16[tl * HD + c8] = pk;
            float* yp = y + (size_t)gtok * CH + h * HD + c8;
            *(float4*)yp       = make_float4(qf[0], qf[1], qf[2], qf[3]);
            *(float4*)(yp + 4) = make_float4(qf[4], qf[5], qf[6], qf[7]);
        }
        __syncthreads();   // kq/v16 of this chunk ready for kv-accum

        for (int j = 0; j < nj; ++j) {
            float kk = u.a.kq[j * 33 + cb];
            uint2 vv = *(const uint2*)&v16[(jc + j) * HD + d0];
            kva[0] = fmaf(kk, h2f_bits((unsigned short)(vv.x & 0xffff)), kva[0]);
            kva[1] = fmaf(kk, h2f_bits((unsigned short)(vv.x >> 16)),    kva[1]);
            kva[2] = fmaf(kk, h2f_bits((unsigned short)(vv.y & 0xffff)), kva[2]);
            kva[3] = fmaf(kk, h2f_bits((unsigned short)(vv.y >> 16)),    kva[3]);
        }
        // next chunk's post-red barrier protects kq reuse
    }

    // kv store + ksum wave-reduction (wave wv owns channels c8..c8+7)
    u.a.kv[cb * HD + d0 + 0] = kva[0];
    u.a.kv[cb * HD + d0 + 1] = kva[1];
    u.a.kv[cb * HD + d0 + 2] = kva[2];
    u.a.kv[cb * HD + d0 + 3] = kva[3];
    #pragma unroll
    for (int i = 0; i < 8; ++i) {
        float s = ksp[i];
        s += __shfl_xor(s, 32, 64);
        s += __shfl_xor(s, 16, 64);
        s += __shfl_xor(s, 8, 64);
        s += __shfl_xor(s, 4, 64);
        s += __shfl_xor(s, 2, 64);
        s += __shfl_xor(s, 1, 64);
        if (lane == 0) ksum_s[c8 + i] = s;
    }
    __threadfence_block();   // qfin y-writes visible to Phase B cross-thread reads
    __syncthreads();

    // ================= Phase B: qfin(y) -> z, att, write y ================
    const int g8 = tid >> 5, c = tid & 31;
    const float ks_c   = ksum_s[c];
    const float bias_c = dwc_b[c];
    float kvc[HD];
    #pragma unroll
    for (int c2 = 0; c2 < HD; ++c2) kvc[c2] = u.a.kv[c2 * HD + c];
    float* kqB = u.a.kq;   // first 4KB reused as [BCH][HD] scratch

    for (int jc = 0; jc < NTOK; jc += BCH) {
        const int nj = min(BCH, NTOK - jc);
        float zreg[4]; int tokr[4];
        #pragma unroll
        for (int i2 = 0; i2 < 4; ++i2) {
            int t = g8 * 4 + i2, j = jc + t;
            bool valid = (t < nj);
            int jj = valid ? j : 0;
            int dz = jj / 49, rem = jj - dz * 49, dy = rem / 7, dxx = rem - dy * 7;
            int tok = ((wd * 7 + dz) * DIM + (wh * 7 + dy)) * DIM + (ww * 7 + dxx);
            float qfv = y[(size_t)tok * CH + h * HD + c];   // qfin cache
            zreg[i2] = 1.f / (grp32_sum(qfv * ks_c) + 1e-6f);
            if (valid) kqB[t * HD + c] = qfv;   // same-wave write->read
            tokr[i2] = tok;
        }
        #pragma unroll
        for (int i2 = 0; i2 < 4; ++i2) {
            int t = g8 * 4 + i2;
            if (t < nj) {
                float att = 0.f;
                #pragma unroll
                for (int c2 = 0; c2 < HD; c2 += 4) {
                    float4 qv = *(const float4*)&kqB[t * HD + c2];
                    att = fmaf(qv.x, kvc[c2],     att);
                    att = fmaf(qv.y, kvc[c2 + 1], att);
                    att = fmaf(qv.z, kvc[c2 + 2], att);
                    att = fmaf(qv.w, kvc[c2 + 3], att);
                }
                y[(size_t)tokr[i2] * CH + h * HD + c] = att * zreg[i2];
            }
        }
        // kqB rows are group-private -> no barrier needed
    }

    __threadfence_block();   // B's y writes visible to conv RMW
    __syncthreads();

    // ---------------- Phase C: depthwise 5x5x5 conv, y += fm + bias ----
    for (int i = tid; i < HD * 125; i += 256) u.dwc[i] = dwc_w[i];
    __syncthreads();

    for (int it = g8; it < 49; it += 8) {
        int dz = it / 7, dy = it - dz * 7;
        float fm[7] = {0.f, 0.f, 0.f, 0.f, 0.f, 0.f, 0.f};
        #pragma unroll
        for (int ka2 = 0; ka2 < 5; ++ka2) {
            int za = dz + ka2 - 2;
            if ((unsigned)za >= 7u) continue;
            #pragma unroll
            for (int kb = 0; kb < 5; ++kb) {
                int zb = dy + kb - 2;
                if ((unsigned)zb >= 7u) continue;
                const unsigned short* vb = &v16[(za * 49 + zb * 7) * HD + c];
                float vr[7];
                #pragma unroll
                for (int xx = 0; xx < 7; ++xx) vr[xx] = h2f_bits(vb[xx * HD]);
                const float* wb = &u.dwc[c * 125 + ka2 * 25 + kb * 5];
                float w0 = wb[0], w1 = wb[1], w2 = wb[2], w3 = wb[3], w4 = wb[4];
                #pragma unroll
                for (int dx2 = 0; dx2 < 7; ++dx2) {
                    if (dx2 - 2 >= 0) fm[dx2] = fmaf(vr[dx2 - 2], w0, fm[dx2]);
                    if (dx2 - 1 >= 0) fm[dx2] = fmaf(vr[dx2 - 1], w1, fm[dx2]);
                    fm[dx2] = fmaf(vr[dx2], w2, fm[dx2]);
                    if (dx2 + 1 <= 6) fm[dx2] = fmaf(vr[dx2 + 1], w3, fm[dx2]);
                    if (dx2 + 2 <= 6) fm[dx2] = fmaf(vr[dx2 + 2], w4, fm[dx2]);
                }
            }
        }
        int tokbase = ((wd * 7 + dz) * DIM + (wh * 7 + dy)) * DIM + ww * 7;
        #pragma unroll
        for (int dx2 = 0; dx2 < 7; ++dx2) {
            float* yp = &y[(size_t)(tokbase + dx2) * CH + h * HD + c];
            *yp += fm[dx2] + bias_c;
        }
    }
}

// In-place projection: d_out <- d_out @ w_proj + b_proj.
__global__ __launch_bounds__(256, 1) void proj_kernel(
    const float* __restrict__ wp, const float* __restrict__ bp,
    float* __restrict__ y)
{
    __shared__ float yt[256 * 97];   // 99328 B, pad->conflict-free
    __shared__ float wl[96 * 96];    // 36864 B

    const int tid = threadIdx.x;
    const int base = blockIdx.x * 256;

    for (int i = tid; i < 96 * 96; i += 256) wl[i] = wp[i];
    for (int i = tid; i < 256 * 96; i += 256) {
        int r = i / 96; int ch2 = i - r * 96;
        yt[r * 97 + ch2] = y[(base + r) * 96 + ch2];
    }
    __syncthreads();

    const int tokg = tid & 63;
    const int outg = tid >> 6;

    float acc[4][24];
    #pragma unroll
    for (int jj = 0; jj < 24; ++jj) {
        float b = bp[outg * 24 + jj];
        acc[0][jj] = b; acc[1][jj] = b; acc[2][jj] = b; acc[3][jj] = b;
    }

    for (int cc = 0; cc < 96; ++cc) {
        float y0 = yt[(tokg)       * 97 + cc];
        float y1 = yt[(tokg + 64)  * 97 + cc];
        float y2 = yt[(tokg + 128) * 97 + cc];
        float y3 = yt[(tokg + 192) * 97 + cc];
        const float* wrow = &wl[cc * 96 + outg * 24];
        #pragma unroll
        for (int jj = 0; jj < 24; ++jj) {
            float wvv = wrow[jj];
            acc[0][jj] = fmaf(y0, wvv, acc[0][jj]);
            acc[1][jj] = fmaf(y1, wvv, acc[1][jj]);
            acc[2][jj] = fmaf(y2, wvv, acc[2][jj]);
            acc[3][jj] = fmaf(y3, wvv, acc[3][jj]);
        }
    }
    __syncthreads();   // all reads done before in-place writes (same block only)

    #pragma unroll
    for (int i = 0; i < 4; ++i) {
        int tok = base + tokg + 64 * i;
        #pragma unroll
        for (int jj = 0; jj < 24; ++jj)
            y[tok * 96 + outg * 24 + jj] = acc[i][jj];
    }
}

extern "C" void kernel_launch(void* const* d_in, const int* in_sizes, int n_in,
                              void* d_out, int out_size, void* d_ws, size_t ws_size,
                              hipStream_t stream) {
    const float* x           = (const float*)d_in[0];
    const float* w_qkv       = (const float*)d_in[1];
    const float* scale_param = (const float*)d_in[2];
    const float* pos_enc     = (const float*)d_in[3];
    const float* dwc_w       = (const float*)d_in[4];
    const float* dwc_b       = (const float*)d_in[5];
    const float* w_proj      = (const float*)d_in[6];
    const float* b_proj      = (const float*)d_in[7];
    float* out = (float*)d_out;

    attn_kernel<<<dim3(NHD * NWIN), dim3(256), 0, stream>>>(
        x, w_qkv, scale_param, pos_enc, dwc_w, dwc_b, out);
    proj_kernel<<<dim3(686), dim3(256), 0, stream>>>(w_proj, b_proj, out);
}

// Round 9
// 430.361 us; speedup vs baseline: 10.4868x; 1.0519x over previous
//
#include <hip/hip_runtime.h>
#include <math.h>

// Problem constants
#define NWIN 512     // 8x8x8 windows
#define NHD  3       // heads
#define NTOK 343     // 7x7x7 tokens per window
#define HD   32      // head dim
#define CH   96      // channels
#define DIM  56      // spatial dim
#define SUB  64      // sub-chunk (transform/kv granularity)
#define BCH  32      // Phase B tokens per chunk

__device__ __forceinline__ unsigned short f2h_bits(float x) {
    _Float16 h = (_Float16)x;                  // RNE
    return __builtin_bit_cast(unsigned short, h);
}
__device__ __forceinline__ float h2f_bits(unsigned short u) {
    return (float)__builtin_bit_cast(_Float16, u);
}

__device__ __forceinline__ float grp32_sum(float v) {
    v += __shfl_xor(v, 16, 32);
    v += __shfl_xor(v, 8, 32);
    v += __shfl_xor(v, 4, 32);
    v += __shfl_xor(v, 2, 32);
    v += __shfl_xor(v, 1, 32);
    return v;
}

// 6 wave-uniform weight float4 loads feed 48 FMAs (2 tokens x 24 outputs).
#define PROCW2(xva, xvb, WR)                                              \
  { const float4 q0 = *(const float4*)(WR);                               \
    const float4 q1 = *(const float4*)((WR) + 4);                         \
    const float4 k0 = *(const float4*)((WR) + CH);                        \
    const float4 k1 = *(const float4*)((WR) + CH + 4);                    \
    const float4 v0 = *(const float4*)((WR) + 2 * CH);                    \
    const float4 v1 = *(const float4*)((WR) + 2 * CH + 4);                \
    aq0[0] = fmaf(xva, q0.x, aq0[0]); aq1[0] = fmaf(xvb, q0.x, aq1[0]);   \
    aq0[1] = fmaf(xva, q0.y, aq0[1]); aq1[1] = fmaf(xvb, q0.y, aq1[1]);   \
    aq0[2] = fmaf(xva, q0.z, aq0[2]); aq1[2] = fmaf(xvb, q0.z, aq1[2]);   \
    aq0[3] = fmaf(xva, q0.w, aq0[3]); aq1[3] = fmaf(xvb, q0.w, aq1[3]);   \
    aq0[4] = fmaf(xva, q1.x, aq0[4]); aq1[4] = fmaf(xvb, q1.x, aq1[4]);   \
    aq0[5] = fmaf(xva, q1.y, aq0[5]); aq1[5] = fmaf(xvb, q1.y, aq1[5]);   \
    aq0[6] = fmaf(xva, q1.z, aq0[6]); aq1[6] = fmaf(xvb, q1.z, aq1[6]);   \
    aq0[7] = fmaf(xva, q1.w, aq0[7]); aq1[7] = fmaf(xvb, q1.w, aq1[7]);   \
    ak0[0] = fmaf(xva, k0.x, ak0[0]); ak1[0] = fmaf(xvb, k0.x, ak1[0]);   \
    ak0[1] = fmaf(xva, k0.y, ak0[1]); ak1[1] = fmaf(xvb, k0.y, ak1[1]);   \
    ak0[2] = fmaf(xva, k0.z, ak0[2]); ak1[2] = fmaf(xvb, k0.z, ak1[2]);   \
    ak0[3] = fmaf(xva, k0.w, ak0[3]); ak1[3] = fmaf(xvb, k0.w, ak1[3]);   \
    ak0[4] = fmaf(xva, k1.x, ak0[4]); ak1[4] = fmaf(xvb, k1.x, ak1[4]);   \
    ak0[5] = fmaf(xva, k1.y, ak0[5]); ak1[5] = fmaf(xvb, k1.y, ak1[5]);   \
    ak0[6] = fmaf(xva, k1.z, ak0[6]); ak1[6] = fmaf(xvb, k1.z, ak1[6]);   \
    ak0[7] = fmaf(xva, k1.w, ak0[7]); ak1[7] = fmaf(xvb, k1.w, ak1[7]);   \
    av0[0] = fmaf(xva, v0.x, av0[0]); av1[0] = fmaf(xvb, v0.x, av1[0]);   \
    av0[1] = fmaf(xva, v0.y, av0[1]); av1[1] = fmaf(xvb, v0.y, av1[1]);   \
    av0[2] = fmaf(xva, v0.z, av0[2]); av1[2] = fmaf(xvb, v0.z, av1[2]);   \
    av0[3] = fmaf(xva, v0.w, av0[3]); av1[3] = fmaf(xvb, v0.w, av1[3]);   \
    av0[4] = fmaf(xva, v1.x, av0[4]); av1[4] = fmaf(xvb, v1.x, av1[4]);   \
    av0[5] = fmaf(xva, v1.y, av0[5]); av1[5] = fmaf(xvb, v1.y, av1[5]);   \
    av0[6] = fmaf(xva, v1.z, av0[6]); av1[6] = fmaf(xvb, v1.z, av1[6]);   \
    av0[7] = fmaf(xva, v1.w, av0[7]); av1[7] = fmaf(xvb, v1.w, av1[7]); }

#define PROC4(XA, XB, WR)                \
    PROCW2((XA).x, (XB).x, (WR));        \
    PROCW2((XA).y, (XB).y, (WR) + 288);  \
    PROCW2((XA).z, (XB).z, (WR) + 576);  \
    PROCW2((XA).w, (XB).w, (WR) + 864);

// transform + norm-reduce + stores + kv-accum for one 64-token sub-chunk.
// Barrier pairing with neighbors is safe: red writes don't alias kq, and
// the barrier after red-write orders prior kv-accum kq-reads before the
// kq overwrite below; the barrier after stores orders stores before reads.
#define FINISH(AQ, AK, AV, TL, TVAL, GTOK, JCS, NJ)                         \
  { int tc_ = (TVAL) ? (TL) : NTOK - 1;                                     \
    float pe[8];                                                            \
    *(float4*)&pe[0] = *(const float4*)(pos_enc + tc_ * HD + c8);           \
    *(float4*)&pe[4] = *(const float4*)(pos_enc + tc_ * HD + c8 + 4);       \
    float k3[8], q3[8];                                                     \
    float n2k = 0.f, n6k = 0.f, n2q = 0.f, n6q = 0.f;                       \
    _Pragma("unroll")                                                       \
    for (int i = 0; i < 8; ++i) {                                           \
        float kk = AK[i] + pe[i];                                           \
        float kp = (fmaxf(kk, 0.f) + 1e-6f) / sp8[i];                       \
        n2k = fmaf(kp, kp, n2k);                                            \
        float t3 = kp * kp * kp; k3[i] = t3;                                \
        n6k = fmaf(t3, t3, n6k);                                            \
        float qp = (fmaxf(AQ[i], 0.f) + 1e-6f) / sp8[i];                    \
        n2q = fmaf(qp, qp, n2q);                                            \
        float u3 = qp * qp * qp; q3[i] = u3;                                \
        n6q = fmaf(u3, u3, n6q);                                            \
    }                                                                       \
    u.a.red[0][wv][lane] = n2k;                                             \
    u.a.red[1][wv][lane] = n6k;                                             \
    u.a.red[2][wv][lane] = n2q;                                             \
    u.a.red[3][wv][lane] = n6q;                                             \
    __syncthreads();                                                        \
    float N2k = u.a.red[0][0][lane] + u.a.red[0][1][lane]                   \
              + u.a.red[0][2][lane] + u.a.red[0][3][lane];                  \
    float N6k = u.a.red[1][0][lane] + u.a.red[1][1][lane]                   \
              + u.a.red[1][2][lane] + u.a.red[1][3][lane];                  \
    float N2q = u.a.red[2][0][lane] + u.a.red[2][1][lane]                   \
              + u.a.red[2][2][lane] + u.a.red[2][3][lane];                  \
    float N6q = u.a.red[3][0][lane] + u.a.red[3][1][lane]                   \
              + u.a.red[3][2][lane] + u.a.red[3][3][lane];                  \
    float sk = sqrtf(N2k / N6k), sq = sqrtf(N2q / N6q);                     \
    if (TVAL) {                                                             \
        float kf[8], qf[8];                                                 \
        _Pragma("unroll")                                                   \
        for (int i = 0; i < 8; ++i) {                                       \
            kf[i] = k3[i] * sk;                                             \
            ksp[i] += kf[i];                                                \
            qf[i] = q3[i] * sq;                                             \
        }                                                                   \
        *(float4*)&u.a.kq[lane * 33 + c8]     = make_float4(kf[0], kf[1], kf[2], kf[3]); \
        *(float4*)&u.a.kq[lane * 33 + c8 + 4] = make_float4(kf[4], kf[5], kf[6], kf[7]); \
        uint4 pk;                                                           \
        pk.x = (unsigned)f2h_bits(AV[0]) | ((unsigned)f2h_bits(AV[1]) << 16); \
        pk.y = (unsigned)f2h_bits(AV[2]) | ((unsigned)f2h_bits(AV[3]) << 16); \
        pk.z = (unsigned)f2h_bits(AV[4]) | ((unsigned)f2h_bits(AV[5]) << 16); \
        pk.w = (unsigned)f2h_bits(AV[6]) | ((unsigned)f2h_bits(AV[7]) << 16); \
        *(uint4*)&v16[(TL) * HD + c8] = pk;                                 \
        float* yp_ = y + (size_t)(GTOK) * CH + h * HD + c8;                 \
        *(float4*)yp_       = make_float4(qf[0], qf[1], qf[2], qf[3]);      \
        *(float4*)(yp_ + 4) = make_float4(qf[4], qf[5], qf[6], qf[7]);      \
    }                                                                       \
    __syncthreads();                                                        \
    for (int j = 0; j < (NJ); ++j) {                                        \
        float kk = u.a.kq[j * 33 + cb];                                     \
        uint2 vv = *(const uint2*)&v16[((JCS) + j) * HD + d0];              \
        kva[0] = fmaf(kk, h2f_bits((unsigned short)(vv.x & 0xffff)), kva[0]); \
        kva[1] = fmaf(kk, h2f_bits((unsigned short)(vv.x >> 16)),    kva[1]); \
        kva[2] = fmaf(kk, h2f_bits((unsigned short)(vv.y & 0xffff)), kva[2]); \
        kva[3] = fmaf(kk, h2f_bits((unsigned short)(vv.y >> 16)),    kva[3]); \
    } }

// One block per (head, window), 256 threads, 4 blocks/CU (LDS 38.8KB).
// Phase A (lane = token, 2 tokens/lane per 128-token chunk): q,k,v GEMM with
// x from global (prefetch-1) and weights via wave-uniform s_load broadcast
// (each weight load feeds 2 tokens -> half the SMEM restream of round 8);
// transforms + kv-accum per 64-token sub-chunk; qfin cached in y.
// Phase B: qfin(y) -> z + att, overwrite y. Phase C: depthwise conv.
__global__ __launch_bounds__(256, 4) void attn_kernel(
    const float* __restrict__ x, const float* __restrict__ w_qkv,
    const float* __restrict__ scale_param, const float* __restrict__ pos_enc,
    const float* __restrict__ dwc_w, const float* __restrict__ dwc_b,
    float* __restrict__ y)
{
    __shared__ __align__(16) unsigned short v16[NTOK * HD];   // 21952 B
    __shared__ __align__(16) union UU {
        struct AA {
            float kq[SUB * 33];          // 8448 B (pitch 33: conflict-free)
            float red[4][4][64];         // 4096 B (cross-wave norm partials)
            float kv[HD * HD];           // 4096 B
        } a;                             // Phase B reuses kq[0..1023] as kqB
        float dwc[HD * 125];             // 16000 B (Phase C alias)
    } u;
    __shared__ float ksum_s[HD];
    __shared__ float sps[HD];
    // total 38848 B -> 4 blocks/CU

    const int tid = threadIdx.x, bid = blockIdx.x;
    const int h = bid >> 9, win = bid & 511;
    const int wd = win >> 6, wh = (win >> 3) & 7, ww = win & 7;
    const int wv = tid >> 6, lane = tid & 63;
    const int c8 = __builtin_amdgcn_readfirstlane((tid >> 6) << 3);

    if (tid < HD) {
        float sv = scale_param[tid];
        sps[tid] = (sv > 20.f) ? sv : log1pf(expf(sv));
    }
    __syncthreads();
    float sp8[8];
    #pragma unroll
    for (int i = 0; i < 8; ++i) sp8[i] = sps[c8 + i];

    const int cb = tid >> 3, d0 = (tid & 7) * 4;   // kv-accum ownership
    float kva[4] = {0.f, 0.f, 0.f, 0.f};
    float ksp[8] = {0.f, 0.f, 0.f, 0.f, 0.f, 0.f, 0.f, 0.f};
    const float* wbase = w_qkv + h * HD + c8;      // wave-uniform

    // ================= Phase A: 3 chunks of 128 tokens =================
    for (int jc = 0; jc < NTOK; jc += 2 * SUB) {
        const int tA = jc + lane;                  // always < NTOK (max 319)
        const int tB = jc + SUB + lane;
        const bool bval = tB < NTOK;
        const int tBc = bval ? tB : NTOK - 1;

        int dzA = tA / 49, remA = tA - dzA * 49, dyA = remA / 7, dxA = remA - dyA * 7;
        const int gtokA = ((wd * 7 + dzA) * DIM + (wh * 7 + dyA)) * DIM + (ww * 7 + dxA);
        int dzB = tBc / 49, remB = tBc - dzB * 49, dyB = remB / 7, dxB = remB - dyB * 7;
        const int gtokB = ((wd * 7 + dzB) * DIM + (wh * 7 + dyB)) * DIM + (ww * 7 + dxB);
        const float4* xgA = (const float4*)(x + (size_t)gtokA * CH);
        const float4* xgB = (const float4*)(x + (size_t)gtokB * CH);

        float aq0[8] = {0,0,0,0,0,0,0,0}, ak0[8] = {0,0,0,0,0,0,0,0}, av0[8] = {0,0,0,0,0,0,0,0};
        float aq1[8] = {0,0,0,0,0,0,0,0}, ak1[8] = {0,0,0,0,0,0,0,0}, av1[8] = {0,0,0,0,0,0,0,0};

        float4 xa = xgA[0], xb = xgB[0];
        #pragma unroll 1
        for (int c4 = 0; c4 < 23; ++c4) {
            float4 xan = xgA[c4 + 1], xbn = xgB[c4 + 1];   // prefetch next
            const float* wr = wbase + c4 * 1152;
            PROC4(xa, xb, wr);
            xa = xan; xb = xbn;
        }
        PROC4(xa, xb, wbase + 23 * 1152);                  // peeled tail

        const int njB = min(SUB, NTOK - jc - SUB);
        FINISH(aq0, ak0, av0, tA,  true, gtokA, jc,       SUB);
        FINISH(aq1, ak1, av1, tBc, bval, gtokB, jc + SUB, njB);
    }

    // kv store + ksum wave-reduction (wave wv owns channels c8..c8+7)
    u.a.kv[cb * HD + d0 + 0] = kva[0];
    u.a.kv[cb * HD + d0 + 1] = kva[1];
    u.a.kv[cb * HD + d0 + 2] = kva[2];
    u.a.kv[cb * HD + d0 + 3] = kva[3];
    #pragma unroll
    for (int i = 0; i < 8; ++i) {
        float s = ksp[i];
        s += __shfl_xor(s, 32, 64);
        s += __shfl_xor(s, 16, 64);
        s += __shfl_xor(s, 8, 64);
        s += __shfl_xor(s, 4, 64);
        s += __shfl_xor(s, 2, 64);
        s += __shfl_xor(s, 1, 64);
        if (lane == 0) ksum_s[c8 + i] = s;
    }
    __threadfence_block();   // qfin y-writes visible to Phase B cross-thread reads
    __syncthreads();

    // ================= Phase B: qfin(y) -> z, att, write y ================
    const int g8 = tid >> 5, c = tid & 31;
    const float ks_c   = ksum_s[c];
    const float bias_c = dwc_b[c];
    float kvc[HD];
    #pragma unroll
    for (int c2 = 0; c2 < HD; ++c2) kvc[c2] = u.a.kv[c2 * HD + c];
    float* kqB = u.a.kq;   // first 4KB reused as [BCH][HD] scratch

    for (int jc = 0; jc < NTOK; jc += BCH) {
        const int nj = min(BCH, NTOK - jc);
        float zreg[4]; int tokr[4];
        #pragma unroll
        for (int i2 = 0; i2 < 4; ++i2) {
            int t = g8 * 4 + i2, j = jc + t;
            bool valid = (t < nj);
            int jj = valid ? j : 0;
            int dz = jj / 49, rem = jj - dz * 49, dy = rem / 7, dxx = rem - dy * 7;
            int tok = ((wd * 7 + dz) * DIM + (wh * 7 + dy)) * DIM + (ww * 7 + dxx);
            float qfv = y[(size_t)tok * CH + h * HD + c];   // qfin cache
            zreg[i2] = 1.f / (grp32_sum(qfv * ks_c) + 1e-6f);
            if (valid) kqB[t * HD + c] = qfv;   // same-wave write->read
            tokr[i2] = tok;
        }
        #pragma unroll
        for (int i2 = 0; i2 < 4; ++i2) {
            int t = g8 * 4 + i2;
            if (t < nj) {
                float att = 0.f;
                #pragma unroll
                for (int c2 = 0; c2 < HD; c2 += 4) {
                    float4 qv = *(const float4*)&kqB[t * HD + c2];
                    att = fmaf(qv.x, kvc[c2],     att);
                    att = fmaf(qv.y, kvc[c2 + 1], att);
                    att = fmaf(qv.z, kvc[c2 + 2], att);
                    att = fmaf(qv.w, kvc[c2 + 3], att);
                }
                y[(size_t)tokr[i2] * CH + h * HD + c] = att * zreg[i2];
            }
        }
        // kqB rows are group-private -> no barrier needed
    }

    __threadfence_block();   // B's y writes visible to conv RMW
    __syncthreads();

    // ---------------- Phase C: depthwise 5x5x5 conv, y += fm + bias ----
    for (int i = tid; i < HD * 125; i += 256) u.dwc[i] = dwc_w[i];
    __syncthreads();

    for (int it = g8; it < 49; it += 8) {
        int dz = it / 7, dy = it - dz * 7;
        float fm[7] = {0.f, 0.f, 0.f, 0.f, 0.f, 0.f, 0.f};
        #pragma unroll
        for (int ka2 = 0; ka2 < 5; ++ka2) {
            int za = dz + ka2 - 2;
            if ((unsigned)za >= 7u) continue;
            #pragma unroll
            for (int kb = 0; kb < 5; ++kb) {
                int zb = dy + kb - 2;
                if ((unsigned)zb >= 7u) continue;
                const unsigned short* vb = &v16[(za * 49 + zb * 7) * HD + c];
                float vr[7];
                #pragma unroll
                for (int xx = 0; xx < 7; ++xx) vr[xx] = h2f_bits(vb[xx * HD]);
                const float* wb = &u.dwc[c * 125 + ka2 * 25 + kb * 5];
                float w0 = wb[0], w1 = wb[1], w2 = wb[2], w3 = wb[3], w4 = wb[4];
                #pragma unroll
                for (int dx2 = 0; dx2 < 7; ++dx2) {
                    if (dx2 - 2 >= 0) fm[dx2] = fmaf(vr[dx2 - 2], w0, fm[dx2]);
                    if (dx2 - 1 >= 0) fm[dx2] = fmaf(vr[dx2 - 1], w1, fm[dx2]);
                    fm[dx2] = fmaf(vr[dx2], w2, fm[dx2]);
                    if (dx2 + 1 <= 6) fm[dx2] = fmaf(vr[dx2 + 1], w3, fm[dx2]);
                    if (dx2 + 2 <= 6) fm[dx2] = fmaf(vr[dx2 + 2], w4, fm[dx2]);
                }
            }
        }
        int tokbase = ((wd * 7 + dz) * DIM + (wh * 7 + dy)) * DIM + ww * 7;
        #pragma unroll
        for (int dx2 = 0; dx2 < 7; ++dx2) {
            float* yp = &y[(size_t)(tokbase + dx2) * CH + h * HD + c];
            *yp += fm[dx2] + bias_c;
        }
    }
}

// In-place projection: d_out <- d_out @ w_proj + b_proj.
__global__ __launch_bounds__(256, 1) void proj_kernel(
    const float* __restrict__ wp, const float* __restrict__ bp,
    float* __restrict__ y)
{
    __shared__ float yt[256 * 97];   // 99328 B, pad->conflict-free
    __shared__ float wl[96 * 96];    // 36864 B

    const int tid = threadIdx.x;
    const int base = blockIdx.x * 256;

    for (int i = tid; i < 96 * 96; i += 256) wl[i] = wp[i];
    for (int i = tid; i < 256 * 96; i += 256) {
        int r = i / 96; int ch2 = i - r * 96;
        yt[r * 97 + ch2] = y[(base + r) * 96 + ch2];
    }
    __syncthreads();

    const int tokg = tid & 63;
    const int outg = tid >> 6;

    float acc[4][24];
    #pragma unroll
    for (int jj = 0; jj < 24; ++jj) {
        float b = bp[outg * 24 + jj];
        acc[0][jj] = b; acc[1][jj] = b; acc[2][jj] = b; acc[3][jj] = b;
    }

    for (int cc = 0; cc < 96; ++cc) {
        float y0 = yt[(tokg)       * 97 + cc];
        float y1 = yt[(tokg + 64)  * 97 + cc];
        float y2 = yt[(tokg + 128) * 97 + cc];
        float y3 = yt[(tokg + 192) * 97 + cc];
        const float* wrow = &wl[cc * 96 + outg * 24];
        #pragma unroll
        for (int jj = 0; jj < 24; ++jj) {
            float wvv = wrow[jj];
            acc[0][jj] = fmaf(y0, wvv, acc[0][jj]);
            acc[1][jj] = fmaf(y1, wvv, acc[1][jj]);
            acc[2][jj] = fmaf(y2, wvv, acc[2][jj]);
            acc[3][jj] = fmaf(y3, wvv, acc[3][jj]);
        }
    }
    __syncthreads();   // all reads done before in-place writes (same block only)

    #pragma unroll
    for (int i = 0; i < 4; ++i) {
        int tok = base + tokg + 64 * i;
        #pragma unroll
        for (int jj = 0; jj < 24; ++jj)
            y[tok * 96 + outg * 24 + jj] = acc[i][jj];
    }
}

extern "C" void kernel_launch(void* const* d_in, const int* in_sizes, int n_in,
                              void* d_out, int out_size, void* d_ws, size_t ws_size,
                              hipStream_t stream) {
    const float* x           = (const float*)d_in[0];
    const float* w_qkv       = (const float*)d_in[1];
    const float* scale_param = (const float*)d_in[2];
    const float* pos_enc     = (const float*)d_in[3];
    const float* dwc_w       = (const float*)d_in[4];
    const float* dwc_b       = (const float*)d_in[5];
    const float* w_proj      = (const float*)d_in[6];
    const float* b_proj      = (const float*)d_in[7];
    float* out = (float*)d_out;

    attn_kernel<<<dim3(NHD * NWIN), dim3(256), 0, stream>>>(
        x, w_qkv, scale_param, pos_enc, dwc_w, dwc_b, out);
    proj_kernel<<<dim3(686), dim3(256), 0, stream>>>(w_proj, b_proj, out);
}

// Round 10
// 383.677 us; speedup vs baseline: 11.7628x; 1.1217x over previous
//
#include <hip/hip_runtime.h>
#include <math.h>

// Problem constants
#define NWIN 512     // 8x8x8 windows
#define NHD  3       // heads
#define NTOK 343     // 7x7x7 tokens per window
#define HD   32      // head dim
#define CH   96      // channels
#define DIM  56      // spatial dim
#define SUB  64      // sub-chunk (transform/kv granularity)
#define BCH  32      // Phase B tokens per chunk

typedef __attribute__((ext_vector_type(8))) _Float16 f16x8;
typedef __attribute__((ext_vector_type(4))) float f32x4;

__device__ __forceinline__ unsigned short f2h_bits(float x) {
    _Float16 h = (_Float16)x;                  // RNE
    return __builtin_bit_cast(unsigned short, h);
}
__device__ __forceinline__ float h2f_bits(unsigned short u) {
    return (float)__builtin_bit_cast(_Float16, u);
}
__device__ __forceinline__ f32x4 mfma16h(f16x8 a, f16x8 b, f32x4 c) {
    return __builtin_amdgcn_mfma_f32_16x16x32_f16(a, b, c, 0, 0, 0);
}

__device__ __forceinline__ float grp32_sum(float v) {
    v += __shfl_xor(v, 16, 32);
    v += __shfl_xor(v, 8, 32);
    v += __shfl_xor(v, 4, 32);
    v += __shfl_xor(v, 2, 32);
    v += __shfl_xor(v, 1, 32);
    return v;
}

// 4 wave-uniform weight float4 loads feed 32 FMAs (2 tokens x 16 q,k outputs).
#define PROCQK2(xva, xvb, WR)                                             \
  { const float4 q0 = *(const float4*)(WR);                               \
    const float4 q1 = *(const float4*)((WR) + 4);                         \
    const float4 k0 = *(const float4*)((WR) + CH);                        \
    const float4 k1 = *(const float4*)((WR) + CH + 4);                    \
    aq0[0] = fmaf(xva, q0.x, aq0[0]); aq1[0] = fmaf(xvb, q0.x, aq1[0]);   \
    aq0[1] = fmaf(xva, q0.y, aq0[1]); aq1[1] = fmaf(xvb, q0.y, aq1[1]);   \
    aq0[2] = fmaf(xva, q0.z, aq0[2]); aq1[2] = fmaf(xvb, q0.z, aq1[2]);   \
    aq0[3] = fmaf(xva, q0.w, aq0[3]); aq1[3] = fmaf(xvb, q0.w, aq1[3]);   \
    aq0[4] = fmaf(xva, q1.x, aq0[4]); aq1[4] = fmaf(xvb, q1.x, aq1[4]);   \
    aq0[5] = fmaf(xva, q1.y, aq0[5]); aq1[5] = fmaf(xvb, q1.y, aq1[5]);   \
    aq0[6] = fmaf(xva, q1.z, aq0[6]); aq1[6] = fmaf(xvb, q1.z, aq1[6]);   \
    aq0[7] = fmaf(xva, q1.w, aq0[7]); aq1[7] = fmaf(xvb, q1.w, aq1[7]);   \
    ak0[0] = fmaf(xva, k0.x, ak0[0]); ak1[0] = fmaf(xvb, k0.x, ak1[0]);   \
    ak0[1] = fmaf(xva, k0.y, ak0[1]); ak1[1] = fmaf(xvb, k0.y, ak1[1]);   \
    ak0[2] = fmaf(xva, k0.z, ak0[2]); ak1[2] = fmaf(xvb, k0.z, ak1[2]);   \
    ak0[3] = fmaf(xva, k0.w, ak0[3]); ak1[3] = fmaf(xvb, k0.w, ak1[3]);   \
    ak0[4] = fmaf(xva, k1.x, ak0[4]); ak1[4] = fmaf(xvb, k1.x, ak1[4]);   \
    ak0[5] = fmaf(xva, k1.y, ak0[5]); ak1[5] = fmaf(xvb, k1.y, ak1[5]);   \
    ak0[6] = fmaf(xva, k1.z, ak0[6]); ak1[6] = fmaf(xvb, k1.z, ak1[6]);   \
    ak0[7] = fmaf(xva, k1.w, ak0[7]); ak1[7] = fmaf(xvb, k1.w, ak1[7]); }

#define PROC4QK(XA, XB, WR)               \
    PROCQK2((XA).x, (XB).x, (WR));        \
    PROCQK2((XA).y, (XB).y, (WR) + 288);  \
    PROCQK2((XA).z, (XB).z, (WR) + 576);  \
    PROCQK2((XA).w, (XB).w, (WR) + 864);

// transform + norm-reduce + stores + kv-accum for one 64-token sub-chunk.
#define FINISH(AQ, AK, TL, TVAL, GTOK, JCS, NJ)                             \
  { int tc_ = (TVAL) ? (TL) : NTOK - 1;                                     \
    float pe[8];                                                            \
    *(float4*)&pe[0] = *(const float4*)(pos_enc + tc_ * HD + c8);           \
    *(float4*)&pe[4] = *(const float4*)(pos_enc + tc_ * HD + c8 + 4);       \
    float k3[8], q3[8];                                                     \
    float n2k = 0.f, n6k = 0.f, n2q = 0.f, n6q = 0.f;                       \
    _Pragma("unroll")                                                       \
    for (int i = 0; i < 8; ++i) {                                           \
        float kk = AK[i] + pe[i];                                           \
        float kp = (fmaxf(kk, 0.f) + 1e-6f) / sp8[i];                       \
        n2k = fmaf(kp, kp, n2k);                                            \
        float t3 = kp * kp * kp; k3[i] = t3;                                \
        n6k = fmaf(t3, t3, n6k);                                            \
        float qp = (fmaxf(AQ[i], 0.f) + 1e-6f) / sp8[i];                    \
        n2q = fmaf(qp, qp, n2q);                                            \
        float u3 = qp * qp * qp; q3[i] = u3;                                \
        n6q = fmaf(u3, u3, n6q);                                            \
    }                                                                       \
    u.a.red[0][wv][lane] = n2k;                                             \
    u.a.red[1][wv][lane] = n6k;                                             \
    u.a.red[2][wv][lane] = n2q;                                             \
    u.a.red[3][wv][lane] = n6q;                                             \
    __syncthreads();                                                        \
    float N2k = u.a.red[0][0][lane] + u.a.red[0][1][lane]                   \
              + u.a.red[0][2][lane] + u.a.red[0][3][lane];                  \
    float N6k = u.a.red[1][0][lane] + u.a.red[1][1][lane]                   \
              + u.a.red[1][2][lane] + u.a.red[1][3][lane];                  \
    float N2q = u.a.red[2][0][lane] + u.a.red[2][1][lane]                   \
              + u.a.red[2][2][lane] + u.a.red[2][3][lane];                  \
    float N6q = u.a.red[3][0][lane] + u.a.red[3][1][lane]                   \
              + u.a.red[3][2][lane] + u.a.red[3][3][lane];                  \
    float sk = sqrtf(N2k / N6k), sq = sqrtf(N2q / N6q);                     \
    if (TVAL) {                                                             \
        float kf[8], qf[8];                                                 \
        _Pragma("unroll")                                                   \
        for (int i = 0; i < 8; ++i) {                                       \
            kf[i] = k3[i] * sk;                                             \
            ksp[i] += kf[i];                                                \
            qf[i] = q3[i] * sq;                                             \
        }                                                                   \
        *(float4*)&u.a.kq[lane * 33 + c8]     = make_float4(kf[0], kf[1], kf[2], kf[3]); \
        *(float4*)&u.a.kq[lane * 33 + c8 + 4] = make_float4(kf[4], kf[5], kf[6], kf[7]); \
        float* yp_ = y + (size_t)(GTOK) * CH + h * HD + c8;                 \
        *(float4*)yp_       = make_float4(qf[0], qf[1], qf[2], qf[3]);      \
        *(float4*)(yp_ + 4) = make_float4(qf[4], qf[5], qf[6], qf[7]);      \
    }                                                                       \
    __syncthreads();                                                        \
    for (int j = 0; j < (NJ); ++j) {                                        \
        float kk = u.a.kq[j * 33 + cb];                                     \
        uint2 vv = *(const uint2*)&v16[((JCS) + j) * HD + d0];              \
        kva[0] = fmaf(kk, h2f_bits((unsigned short)(vv.x & 0xffff)), kva[0]); \
        kva[1] = fmaf(kk, h2f_bits((unsigned short)(vv.x >> 16)),    kva[1]); \
        kva[2] = fmaf(kk, h2f_bits((unsigned short)(vv.y & 0xffff)), kva[2]); \
        kva[3] = fmaf(kk, h2f_bits((unsigned short)(vv.y >> 16)),    kva[3]); \
    } }

// One block per (head, window), 256 threads, 4 blocks/CU (LDS 38.8KB).
// Phase A0: v = x @ w_v via fp16 MFMA (w_v fragments built in-kernel; x
//           staged fp16 in LDS aliasing kq/red) -> v16 for all 343 tokens.
// Phase A:  q,k GEMM (lane=token, 2 tokens/lane, s_load weights);
//           transforms + kv-accum per 64-token sub-chunk; qfin cached in y.
// Phase B:  qfin(y) -> z + att, overwrite y. Phase C: depthwise conv.
__global__ __launch_bounds__(256, 4) void attn_kernel(
    const float* __restrict__ x, const float* __restrict__ w_qkv,
    const float* __restrict__ scale_param, const float* __restrict__ pos_enc,
    const float* __restrict__ dwc_w, const float* __restrict__ dwc_b,
    float* __restrict__ y)
{
    __shared__ __align__(16) unsigned short v16[NTOK * HD];   // 21952 B
    __shared__ __align__(16) union UU {
        struct AA {
            float kq[SUB * 33];          // 8448 B (pitch 33: conflict-free)
            float red[4][4][64];         // 4096 B (cross-wave norm partials)
            float kv[HD * HD];           // 4096 B
        } a;                             // Phase B reuses kq[0..1023] as kqB
        unsigned short xstage[SUB * CH]; // 12288 B (Phase A0 alias of kq+red)
        float dwc[HD * 125];             // 16000 B (Phase C alias)
    } u;
    __shared__ float ksum_s[HD];
    __shared__ float sps[HD];
    // total 38848 B -> 4 blocks/CU

    const int tid = threadIdx.x, bid = blockIdx.x;
    const int h = bid >> 9, win = bid & 511;
    const int wd = win >> 6, wh = (win >> 3) & 7, ww = win & 7;
    const int wv = tid >> 6, lane = tid & 63;
    const int c8 = __builtin_amdgcn_readfirstlane((tid >> 6) << 3);

    // ---- build w_v fp16 B-fragments in-registers (B[k][col], k contiguous 8)
    f16x8 bv[2][3];
    {
        const int kg0 = (lane >> 4) * 8;
        const int cl  = lane & 15;
        #pragma unroll
        for (int nt = 0; nt < 2; ++nt) {
            #pragma unroll
            for (int ks = 0; ks < 3; ++ks) {
                union { _Float16 hh[8]; f16x8 v; } t;
                #pragma unroll
                for (int e = 0; e < 8; ++e)
                    t.hh[e] = (_Float16)w_qkv[(ks * 32 + kg0 + e) * 288
                                              + 2 * CH + h * HD + nt * 16 + cl];
                bv[nt][ks] = t.v;
            }
        }
    }

    if (tid < HD) {
        float sv = scale_param[tid];
        sps[tid] = (sv > 20.f) ? sv : log1pf(expf(sv));
    }
    __syncthreads();
    float sp8[8];
    #pragma unroll
    for (int i = 0; i < 8; ++i) sp8[i] = sps[c8 + i];

    // ================= Phase A0: v via fp16 MFMA -> v16 =================
    for (int s = 0; s < NTOK; s += SUB) {
        const int nrow = min(SUB, NTOK - s);
        // stage x rows as fp16 (coalesced: 24 float4 per row)
        for (int i = tid; i < nrow * 24; i += 256) {
            int r = i / 24, c4 = i - r * 24;
            int j2 = s + r;
            int dz = j2 / 49, rem = j2 - dz * 49, dy = rem / 7, dxx = rem - dy * 7;
            int gtok = ((wd * 7 + dz) * DIM + (wh * 7 + dy)) * DIM + (ww * 7 + dxx);
            float4 xv = ((const float4*)(x + (size_t)gtok * CH))[c4];
            uint2 p;
            p.x = (unsigned)f2h_bits(xv.x) | ((unsigned)f2h_bits(xv.y) << 16);
            p.y = (unsigned)f2h_bits(xv.z) | ((unsigned)f2h_bits(xv.w) << 16);
            *(uint2*)&u.xstage[r * CH + c4 * 4] = p;
        }
        __syncthreads();

        // wave wv: m-tile rows wv*16..+15 ; 2 n-tiles x K=96
        const int arow = wv * 16 + (lane & 15);
        const int kb8  = (lane >> 4) * 8;
        f16x8 ah[3];
        #pragma unroll
        for (int ks = 0; ks < 3; ++ks)
            ah[ks] = *(const f16x8*)&u.xstage[arow * CH + ks * 32 + kb8];
        const int rbase = wv * 16 + (lane >> 4) * 4;
        #pragma unroll
        for (int nt = 0; nt < 2; ++nt) {
            f32x4 acc = {0.f, 0.f, 0.f, 0.f};
            #pragma unroll
            for (int ks = 0; ks < 3; ++ks)
                acc = mfma16h(ah[ks], bv[nt][ks], acc);
            int col = nt * 16 + (lane & 15);
            #pragma unroll
            for (int j = 0; j < 4; ++j) {
                int r = rbase + j;
                if (s + r < NTOK)
                    v16[(s + r) * HD + col] = f2h_bits(acc[j]);
            }
        }
        __syncthreads();   // v16/xstage ready before next stage overwrite
    }

    const int cb = tid >> 3, d0 = (tid & 7) * 4;   // kv-accum ownership
    float kva[4] = {0.f, 0.f, 0.f, 0.f};
    float ksp[8] = {0.f, 0.f, 0.f, 0.f, 0.f, 0.f, 0.f, 0.f};
    const float* wbase = w_qkv + h * HD + c8;      // wave-uniform

    // ================= Phase A: q,k (3 chunks of 128 tokens) ============
    for (int jc = 0; jc < NTOK; jc += 2 * SUB) {
        const int tA = jc + lane;                  // always < NTOK (max 319)
        const int tB = jc + SUB + lane;
        const bool bval = tB < NTOK;
        const int tBc = bval ? tB : NTOK - 1;

        int dzA = tA / 49, remA = tA - dzA * 49, dyA = remA / 7, dxA = remA - dyA * 7;
        const int gtokA = ((wd * 7 + dzA) * DIM + (wh * 7 + dyA)) * DIM + (ww * 7 + dxA);
        int dzB = tBc / 49, remB = tBc - dzB * 49, dyB = remB / 7, dxB = remB - dyB * 7;
        const int gtokB = ((wd * 7 + dzB) * DIM + (wh * 7 + dyB)) * DIM + (ww * 7 + dxB);
        const float4* xgA = (const float4*)(x + (size_t)gtokA * CH);
        const float4* xgB = (const float4*)(x + (size_t)gtokB * CH);

        float aq0[8] = {0,0,0,0,0,0,0,0}, ak0[8] = {0,0,0,0,0,0,0,0};
        float aq1[8] = {0,0,0,0,0,0,0,0}, ak1[8] = {0,0,0,0,0,0,0,0};

        float4 xa = xgA[0], xb = xgB[0];
        #pragma unroll 1
        for (int c4 = 0; c4 < 23; ++c4) {
            float4 xan = xgA[c4 + 1], xbn = xgB[c4 + 1];   // prefetch next
            const float* wr = wbase + c4 * 1152;
            PROC4QK(xa, xb, wr);
            xa = xan; xb = xbn;
        }
        PROC4QK(xa, xb, wbase + 23 * 1152);                // peeled tail

        const int njB = min(SUB, NTOK - jc - SUB);
        FINISH(aq0, ak0, tA,  true, gtokA, jc,       SUB);
        FINISH(aq1, ak1, tBc, bval, gtokB, jc + SUB, njB);
    }

    // kv store + ksum wave-reduction (wave wv owns channels c8..c8+7)
    u.a.kv[cb * HD + d0 + 0] = kva[0];
    u.a.kv[cb * HD + d0 + 1] = kva[1];
    u.a.kv[cb * HD + d0 + 2] = kva[2];
    u.a.kv[cb * HD + d0 + 3] = kva[3];
    #pragma unroll
    for (int i = 0; i < 8; ++i) {
        float s = ksp[i];
        s += __shfl_xor(s, 32, 64);
        s += __shfl_xor(s, 16, 64);
        s += __shfl_xor(s, 8, 64);
        s += __shfl_xor(s, 4, 64);
        s += __shfl_xor(s, 2, 64);
        s += __shfl_xor(s, 1, 64);
        if (lane == 0) ksum_s[c8 + i] = s;
    }
    __threadfence_block();   // qfin y-writes visible to Phase B cross-thread reads
    __syncthreads();

    // ================= Phase B: qfin(y) -> z, att, write y ================
    const int g8 = tid >> 5, c = tid & 31;
    const float ks_c   = ksum_s[c];
    const float bias_c = dwc_b[c];
    float kvc[HD];
    #pragma unroll
    for (int c2 = 0; c2 < HD; ++c2) kvc[c2] = u.a.kv[c2 * HD + c];
    float* kqB = u.a.kq;   // first 4KB reused as [BCH][HD] scratch

    for (int jc = 0; jc < NTOK; jc += BCH) {
        const int nj = min(BCH, NTOK - jc);
        float zreg[4]; int tokr[4];
        #pragma unroll
        for (int i2 = 0; i2 < 4; ++i2) {
            int t = g8 * 4 + i2, j = jc + t;
            bool valid = (t < nj);
            int jj = valid ? j : 0;
            int dz = jj / 49, rem = jj - dz * 49, dy = rem / 7, dxx = rem - dy * 7;
            int tok = ((wd * 7 + dz) * DIM + (wh * 7 + dy)) * DIM + (ww * 7 + dxx);
            float qfv = y[(size_t)tok * CH + h * HD + c];   // qfin cache
            zreg[i2] = 1.f / (grp32_sum(qfv * ks_c) + 1e-6f);
            if (valid) kqB[t * HD + c] = qfv;   // same-wave write->read
            tokr[i2] = tok;
        }
        #pragma unroll
        for (int i2 = 0; i2 < 4; ++i2) {
            int t = g8 * 4 + i2;
            if (t < nj) {
                float att = 0.f;
                #pragma unroll
                for (int c2 = 0; c2 < HD; c2 += 4) {
                    float4 qv = *(const float4*)&kqB[t * HD + c2];
                    att = fmaf(qv.x, kvc[c2],     att);
                    att = fmaf(qv.y, kvc[c2 + 1], att);
                    att = fmaf(qv.z, kvc[c2 + 2], att);
                    att = fmaf(qv.w, kvc[c2 + 3], att);
                }
                y[(size_t)tokr[i2] * CH + h * HD + c] = att * zreg[i2];
            }
        }
        // kqB rows are group-private -> no barrier needed
    }

    __threadfence_block();   // B's y writes visible to conv RMW
    __syncthreads();

    // ---------------- Phase C: depthwise 5x5x5 conv, y += fm + bias ----
    for (int i = tid; i < HD * 125; i += 256) u.dwc[i] = dwc_w[i];
    __syncthreads();

    for (int it = g8; it < 49; it += 8) {
        int dz = it / 7, dy = it - dz * 7;
        float fm[7] = {0.f, 0.f, 0.f, 0.f, 0.f, 0.f, 0.f};
        #pragma unroll
        for (int ka2 = 0; ka2 < 5; ++ka2) {
            int za = dz + ka2 - 2;
            if ((unsigned)za >= 7u) continue;
            #pragma unroll
            for (int kb = 0; kb < 5; ++kb) {
                int zb = dy + kb - 2;
                if ((unsigned)zb >= 7u) continue;
                const unsigned short* vb = &v16[(za * 49 + zb * 7) * HD + c];
                float vr[7];
                #pragma unroll
                for (int xx = 0; xx < 7; ++xx) vr[xx] = h2f_bits(vb[xx * HD]);
                const float* wb = &u.dwc[c * 125 + ka2 * 25 + kb * 5];
                float w0 = wb[0], w1 = wb[1], w2 = wb[2], w3 = wb[3], w4 = wb[4];
                #pragma unroll
                for (int dx2 = 0; dx2 < 7; ++dx2) {
                    if (dx2 - 2 >= 0) fm[dx2] = fmaf(vr[dx2 - 2], w0, fm[dx2]);
                    if (dx2 - 1 >= 0) fm[dx2] = fmaf(vr[dx2 - 1], w1, fm[dx2]);
                    fm[dx2] = fmaf(vr[dx2], w2, fm[dx2]);
                    if (dx2 + 1 <= 6) fm[dx2] = fmaf(vr[dx2 + 1], w3, fm[dx2]);
                    if (dx2 + 2 <= 6) fm[dx2] = fmaf(vr[dx2 + 2], w4, fm[dx2]);
                }
            }
        }
        int tokbase = ((wd * 7 + dz) * DIM + (wh * 7 + dy)) * DIM + ww * 7;
        #pragma unroll
        for (int dx2 = 0; dx2 < 7; ++dx2) {
            float* yp = &y[(size_t)(tokbase + dx2) * CH + h * HD + c];
            *yp += fm[dx2] + bias_c;
        }
    }
}

// In-place projection: d_out <- d_out @ w_proj + b_proj.
__global__ __launch_bounds__(256, 1) void proj_kernel(
    const float* __restrict__ wp, const float* __restrict__ bp,
    float* __restrict__ y)
{
    __shared__ float yt[256 * 97];   // 99328 B, pad->conflict-free
    __shared__ float wl[96 * 96];    // 36864 B

    const int tid = threadIdx.x;
    const int base = blockIdx.x * 256;

    for (int i = tid; i < 96 * 96; i += 256) wl[i] = wp[i];
    for (int i = tid; i < 256 * 96; i += 256) {
        int r = i / 96; int ch2 = i - r * 96;
        yt[r * 97 + ch2] = y[(base + r) * 96 + ch2];
    }
    __syncthreads();

    const int tokg = tid & 63;
    const int outg = tid >> 6;

    float acc[4][24];
    #pragma unroll
    for (int jj = 0; jj < 24; ++jj) {
        float b = bp[outg * 24 + jj];
        acc[0][jj] = b; acc[1][jj] = b; acc[2][jj] = b; acc[3][jj] = b;
    }

    for (int cc = 0; cc < 96; ++cc) {
        float y0 = yt[(tokg)       * 97 + cc];
        float y1 = yt[(tokg + 64)  * 97 + cc];
        float y2 = yt[(tokg + 128) * 97 + cc];
        float y3 = yt[(tokg + 192) * 97 + cc];
        const float* wrow = &wl[cc * 96 + outg * 24];
        #pragma unroll
        for (int jj = 0; jj < 24; ++jj) {
            float wvv = wrow[jj];
            acc[0][jj] = fmaf(y0, wvv, acc[0][jj]);
            acc[1][jj] = fmaf(y1, wvv, acc[1][jj]);
            acc[2][jj] = fmaf(y2, wvv, acc[2][jj]);
            acc[3][jj] = fmaf(y3, wvv, acc[3][jj]);
        }
    }
    __syncthreads();   // all reads done before in-place writes (same block only)

    #pragma unroll
    for (int i = 0; i < 4; ++i) {
        int tok = base + tokg + 64 * i;
        #pragma unroll
        for (int jj = 0; jj < 24; ++jj)
            y[tok * 96 + outg * 24 + jj] = acc[i][jj];
    }
}

extern "C" void kernel_launch(void* const* d_in, const int* in_sizes, int n_in,
                              void* d_out, int out_size, void* d_ws, size_t ws_size,
                              hipStream_t stream) {
    const float* x           = (const float*)d_in[0];
    const float* w_qkv       = (const float*)d_in[1];
    const float* scale_param = (const float*)d_in[2];
    const float* pos_enc     = (const float*)d_in[3];
    const float* dwc_w       = (const float*)d_in[4];
    const float* dwc_b       = (const float*)d_in[5];
    const float* w_proj      = (const float*)d_in[6];
    const float* b_proj      = (const float*)d_in[7];
    float* out = (float*)d_out;

    attn_kernel<<<dim3(NHD * NWIN), dim3(256), 0, stream>>>(
        x, w_qkv, scale_param, pos_enc, dwc_w, dwc_b, out);
    proj_kernel<<<dim3(686), dim3(256), 0, stream>>>(w_proj, b_proj, out);
}